// Round 3
// baseline (994.051 us; speedup 1.0000x reference)
//
#include <hip/hip_runtime.h>

// ---------------------------------------------------------------------------
// FoldIteration (AlphaFold IPA + transition + rigid update).
// N=768, C=384, C2=128, H=12, PQK=4, PV=8, CQK=16, CV=16. Out: [768, 396].
// Dtype-dual: probes input dtype (f32 vs bf16) on device.
// R3: fused logits+softmax (no logits round-trip), restructured k3b,
//     64x64 GEMM tiles.
// ---------------------------------------------------------------------------

typedef unsigned short bfu;
typedef unsigned int u32;

__device__ __forceinline__ float bf2f(bfu u) {
    return __uint_as_float(((u32)u) << 16);
}
__device__ __forceinline__ bfu f2bf(float f) {
    u32 x = __float_as_uint(f);
    u32 r = x + 0x7fffu + ((x >> 16) & 1u);
    return (bfu)(r >> 16);
}
__device__ __forceinline__ float bflo(u32 u) { return __uint_as_float(u << 16); }
__device__ __forceinline__ float bfhi(u32 u) { return __uint_as_float(u & 0xffff0000u); }

// ---- workspace layout (bytes) ----
#define OFF_PL      0u               // pl bf16 [768][1152]
#define OFF_FQ      1769472u         // fq f32 [768][384]
#define OFF_GKT     2949120u         // gkT f32 [384][768]   (transposed!)
#define OFF_VST     4128768u         // vsT bf16 [192][768]
#define OFF_VGT     4423680u         // vgT bf16 [288][768]
#define OFF_ATTN    4866048u         // attn f32 [768][12][768]
#define OFF_FINAL   33177600u        // final bf16 [768][2112]
#define OFF_ATTNOUT 36421632u        // bf16 [768][384]
#define OFF_ACT     37011456u        // bf16 [768][384]
#define OFF_X1      37601280u        // bf16 [768][384]
#define OFF_X2      38191104u        // bf16 [768][384] (act2 after gemm3)
#define OFF_WCAT    38780928u        // bf16 [384][1152]
#define OFF_BCAT    39665664u        // bf16 [1152]
#define OFF_CONV    39667968u        // bf16 canonical copies of 30 small inputs
#define OFF_FLAG    43684288u        // u32 flags[2]

#define CONV_TOTAL 2008158

struct P30 { const void* p[30]; };

static __device__ const int kEnd[30] = {
    294912, 295680, 302592, 304896, 360192, 360336, 415632, 415776,
    526368, 526656, 600384, 674112, 747840, 747852, 749388, 749400,
    1560408, 1560792, 1561176, 1561560, 1709016, 1709400, 1856856, 1857240,
    2004696, 2005080, 2005464, 2005848, 2008152, 2008158
};

// ---------------------------------------------------------------------------
__global__ __launch_bounds__(256) void k_convert(P30 ps, bfu* __restrict__ conv,
                                                 u32* __restrict__ flags) {
    u32 pm = *(const u32*)ps.p[1];    // mask[0]
    u32 pp = *(const u32*)ps.p[18];   // ln1_s[0]
    u32 fA = (pm == 0x3F800000u) ? 1u : 0u;
    u32 fB = (pp == 0x3F800000u) ? 1u : 0u;
    int idx = blockIdx.x * 256 + threadIdx.x;
    if (idx == 0) { flags[0] = fA; flags[1] = fA & fB; }
    if (idx >= CONV_TOTAL) return;
    int t = 0;
    while (idx >= kEnd[t]) ++t;
    int local = idx - (t ? kEnd[t - 1] : 0);
    u32 f = (t < 4) ? fA : fB;
    float v = f ? ((const float*)ps.p[t])[local]
                : bf2f(((const bfu*)ps.p[t])[local]);
    conv[idx] = f2bf(v);
}

// ---------------------------------------------------------------------------
__global__ __launch_bounds__(256) void k_concat(
    const bfu* __restrict__ wqs, const bfu* __restrict__ wks, const bfu* __restrict__ wvs,
    const bfu* __restrict__ wqp, const bfu* __restrict__ bqp,
    const bfu* __restrict__ wkp, const bfu* __restrict__ bkp,
    const bfu* __restrict__ wvp, const bfu* __restrict__ bvp,
    bfu* __restrict__ wcat, bfu* __restrict__ bcat) {
    int idx = blockIdx.x * 256 + threadIdx.x;
    if (idx < 384 * 1152) {
        int row = idx / 1152, col = idx - row * 1152;
        bfu v;
        if      (col < 192) v = wqs[row * 192 + col];
        else if (col < 384) v = wks[row * 192 + col - 192];
        else if (col < 576) v = wvs[row * 192 + col - 384];
        else if (col < 720) v = wqp[row * 144 + col - 576];
        else if (col < 864) v = wkp[row * 144 + col - 720];
        else                v = wvp[row * 288 + col - 864];
        wcat[idx] = v;
    } else if (idx < 384 * 1152 + 1152) {
        int col = idx - 384 * 1152;
        bfu v;
        if      (col < 576) v = 0;
        else if (col < 720) v = bqp[col - 576];
        else if (col < 864) v = bkp[col - 720];
        else                v = bvp[col - 864];
        bcat[col] = v;
    }
}

// ---------------------------------------------------------------------------
// 64x64 tiled GEMM, 256 threads, 4x4 micro, BK=32. K%32==0, M%64==0, N%64==0.
// ---------------------------------------------------------------------------
template <int RELU>
__global__ __launch_bounds__(256) void k_gemm64(
    const bfu* __restrict__ A, const bfu* __restrict__ W, const bfu* __restrict__ bias,
    bfu* __restrict__ out, int K, int M) {
    __shared__ float As[32][69];   // As[k][row]
    __shared__ float Ws[32][69];   // Ws[k][col]
    int t = threadIdx.x;
    int c0 = blockIdx.x * 64, r0 = blockIdx.y * 64;
    int tr = t >> 4, tc = t & 15;
    float acc[4][4] = {};
    for (int kc = 0; kc < K; kc += 32) {
#pragma unroll
        for (int i = 0; i < 4; ++i) {
            int idx = t + i * 256;
            int r = idx >> 4, c2 = idx & 15;
            u32 u = *(const u32*)&A[(size_t)(r0 + r) * K + kc + 2 * c2];
            As[2 * c2][r] = bflo(u); As[2 * c2 + 1][r] = bfhi(u);
        }
#pragma unroll
        for (int i = 0; i < 4; ++i) {
            int idx = t + i * 256;
            int r = idx >> 5, c2 = idx & 31;
            u32 u = *(const u32*)&W[(size_t)(kc + r) * M + c0 + 2 * c2];
            Ws[r][2 * c2] = bflo(u); Ws[r][2 * c2 + 1] = bfhi(u);
        }
        __syncthreads();
#pragma unroll
        for (int kk = 0; kk < 32; ++kk) {
            float x[4], w[4];
#pragma unroll
            for (int j = 0; j < 4; ++j) { x[j] = As[kk][4 * tr + j]; w[j] = Ws[kk][4 * tc + j]; }
#pragma unroll
            for (int a = 0; a < 4; ++a)
#pragma unroll
                for (int b = 0; b < 4; ++b) acc[a][b] += x[a] * w[b];
        }
        __syncthreads();
    }
    float bv[4];
#pragma unroll
    for (int b = 0; b < 4; ++b) bv[b] = bf2f(bias[c0 + 4 * tc + b]);
#pragma unroll
    for (int a = 0; a < 4; ++a) {
        float v[4];
#pragma unroll
        for (int b = 0; b < 4; ++b) {
            v[b] = acc[a][b] + bv[b];
            if (RELU) v[b] = fmaxf(v[b], 0.f);
        }
        uint2 pk;
        pk.x = (u32)f2bf(v[0]) | ((u32)f2bf(v[1]) << 16);
        pk.y = (u32)f2bf(v[2]) | ((u32)f2bf(v[3]) << 16);
        *(uint2*)&out[(size_t)(r0 + 4 * tr + a) * M + c0 + 4 * tc] = pk;
    }
}

// ---------------------------------------------------------------------------
// Per-residue rigid transforms + augmented QK features (gk stored TRANSPOSED).
// fq[n][h*32+j] = [ 0.25*qs(16) | qg(12) | -0.5*pw*qn | 1 | b2d | 0 ]
// gkT[h*32+j][n] = [ ks(16)     | pw*kg(12) | 1 | -0.5*pw*kn | 1 | 0 ]
// ---------------------------------------------------------------------------
__global__ __launch_bounds__(64) void k_rigid(
    const bfu* __restrict__ pl, const bfu* __restrict__ rot, const bfu* __restrict__ trans,
    const bfu* __restrict__ tpw, const bfu* __restrict__ b2d,
    float* __restrict__ fq, float* __restrict__ gkT,
    bfu* __restrict__ vsT, bfu* __restrict__ vgT) {
    int n = blockIdx.x, t = threadIdx.x;
    __shared__ float pls[1152];
    __shared__ float qgs[144], kgs[144];
    __shared__ float rs[9], ts3[3], pws[12], qns[12], kns[12];
    for (int i = t; i < 1152; i += 64) pls[i] = bf2f(pl[(size_t)n * 1152 + i]);
    if (t < 9)  rs[t] = bf2f(rot[n * 9 + t]);
    if (t < 3)  ts3[t] = bf2f(trans[n * 3 + t]);
    if (t < 12) pws[t] = 0.23570226039551584f * log1pf(expf(bf2f(tpw[t])));
    __syncthreads();
    for (int idx = t; idx < 144; idx += 64) {
        int h = idx / 12, r = idx - h * 12, p = r / 3, i = r - p * 3;
        float q0 = pls[576 + h * 12 + p], q1 = pls[576 + h * 12 + 4 + p], q2 = pls[576 + h * 12 + 8 + p];
        qgs[idx] = rs[i * 3 + 0] * q0 + rs[i * 3 + 1] * q1 + rs[i * 3 + 2] * q2 + ts3[i];
        float k0 = pls[720 + h * 12 + p], k1 = pls[720 + h * 12 + 4 + p], k2 = pls[720 + h * 12 + 8 + p];
        kgs[idx] = rs[i * 3 + 0] * k0 + rs[i * 3 + 1] * k1 + rs[i * 3 + 2] * k2 + ts3[i];
    }
    for (int idx = t; idx < 288; idx += 64) {
        int h = idx / 24, r = idx - h * 24, p = r / 3, i = r - p * 3;
        float v0 = pls[864 + h * 24 + p], v1 = pls[864 + h * 24 + 8 + p], v2 = pls[864 + h * 24 + 16 + p];
        float v = rs[i * 3 + 0] * v0 + rs[i * 3 + 1] * v1 + rs[i * 3 + 2] * v2 + ts3[i];
        vgT[(size_t)idx * 768 + n] = f2bf(v);
    }
    __syncthreads();
    if (t < 12) {
        float s = 0;
        for (int j = 0; j < 12; ++j) s += qgs[t * 12 + j] * qgs[t * 12 + j];
        qns[t] = s;
        s = 0;
        for (int j = 0; j < 12; ++j) s += kgs[t * 12 + j] * kgs[t * 12 + j];
        kns[t] = s;
    }
    __syncthreads();
    for (int idx = t; idx < 12 * 32; idx += 64) {
        int h = idx >> 5, j = idx & 31;
        float fv, gv;
        if (j < 16)      { fv = 0.25f * pls[h * 16 + j];      gv = pls[192 + h * 16 + j]; }
        else if (j < 28) { fv = qgs[h * 12 + j - 16];         gv = pws[h] * kgs[h * 12 + j - 16]; }
        else if (j == 28){ fv = -0.5f * pws[h] * qns[h];      gv = 1.0f; }
        else if (j == 29){ fv = 1.0f;                          gv = -0.5f * pws[h] * kns[h]; }
        else if (j == 30){ fv = bf2f(b2d[h]);                  gv = 1.0f; }
        else             { fv = 0.0f;                          gv = 0.0f; }
        fq[(size_t)n * 384 + idx] = fv;
        gkT[(size_t)idx * 768 + n] = gv;
    }
    for (int idx = t; idx < 192; idx += 64)
        vsT[(size_t)idx * 768 + n] = f2bf(pls[384 + idx]);
}

// ---------------------------------------------------------------------------
// k_fused: per-q block. logits[h][k] = fq[q]·gk[k] + in2d@w2d - mask, *sqrt(1/3),
// softmax over k, write attn f32 [q][12][768]. No logits round-trip.
// ---------------------------------------------------------------------------
__global__ __launch_bounds__(256) void k_fused(
    const float* __restrict__ fq, const float* __restrict__ gkT,
    const void* __restrict__ in2dv, const bfu* __restrict__ w2d,
    const bfu* __restrict__ mask, float* __restrict__ attn,
    const u32* __restrict__ flags) {
    int q = blockIdx.x, t = threadIdx.x;
    bool f32m = flags[0] != 0u;
    __shared__ float lg[12 * 776];                 // 37.2 KB
    __shared__ __align__(16) float w2ds[12 * 128]; // [h][c] 6 KB
    __shared__ __align__(16) float fqs[384];       // 1.5 KB
    for (int i = t; i < 1536; i += 256) {
        int cc = i / 12, hh = i - cc * 12;
        w2ds[hh * 128 + cc] = bf2f(w2d[i]);
    }
    for (int i = t; i < 384; i += 256) fqs[i] = fq[(size_t)q * 384 + i];
    float mq = bf2f(mask[q]);
    __syncthreads();

    for (int ch = 0; ch < 3; ++ch) {
        int k = ch * 256 + t;
        float acc[12] = {};
        size_t base = ((size_t)q * 768 + k) * 128;
        if (f32m) {
            const float4* p = (const float4*)((const float*)in2dv + base);
#pragma unroll 8
            for (int cb = 0; cb < 32; ++cb) {
                float4 u = p[cb];
#pragma unroll
                for (int h = 0; h < 12; ++h) {
                    float4 w = *(const float4*)&w2ds[h * 128 + cb * 4];
                    acc[h] += u.x * w.x + u.y * w.y + u.z * w.z + u.w * w.w;
                }
            }
        } else {
            const uint2* p = (const uint2*)((const bfu*)in2dv + base);
#pragma unroll 8
            for (int cb = 0; cb < 32; ++cb) {
                uint2 u = p[cb];
                float f0 = bflo(u.x), f1 = bfhi(u.x), f2 = bflo(u.y), f3 = bfhi(u.y);
#pragma unroll
                for (int h = 0; h < 12; ++h) {
                    float4 w = *(const float4*)&w2ds[h * 128 + cb * 4];
                    acc[h] += f0 * w.x + f1 * w.y + f2 * w.z + f3 * w.w;
                }
            }
        }
        float mk = bf2f(mask[k]);
        float mterm = 100000.0f * (1.0f - mq * mk);
#pragma unroll 1
        for (int h = 0; h < 12; ++h) {
            float s = 0.f;
            const float* g = gkT + (size_t)(h * 32) * 768 + k;
            const float* f = fqs + h * 32;
#pragma unroll 8
            for (int c = 0; c < 32; ++c) s += g[(size_t)c * 768] * f[c];
            lg[h * 776 + k] = (s + acc[h] - mterm) * 0.5773502691896258f;
        }
    }
    __syncthreads();

    // softmax over k per head (16-thread groups per head)
    if (t < 192) {
        int h = t >> 4, g = t & 15;
        float m = -1e30f;
        for (int i = 0; i < 48; ++i) m = fmaxf(m, lg[h * 776 + g + i * 16]);
#pragma unroll
        for (int off = 1; off < 16; off <<= 1) m = fmaxf(m, __shfl_xor(m, off));
        float s = 0.f;
        for (int i = 0; i < 48; ++i) {
            float v = __expf(lg[h * 776 + g + i * 16] - m);
            lg[h * 776 + g + i * 16] = v;
            s += v;
        }
#pragma unroll
        for (int off = 1; off < 16; off <<= 1) s += __shfl_xor(s, off);
        float rinv = 1.0f / s;
        for (int i = 0; i < 48; ++i) lg[h * 776 + g + i * 16] *= rinv;
    }
    __syncthreads();
    for (int h = 0; h < 12; ++h)
        for (int k = t; k < 768; k += 256)
            attn[(size_t)q * 9216 + h * 768 + k] = lg[h * 776 + k];
}

// ---------------------------------------------------------------------------
// k3b: per-q block. res_2d (stream in2d from global), res_scalar, rp_g,
// rigid-inverse + norms, assemble final[q][2112] bf16.
// ---------------------------------------------------------------------------
__global__ __launch_bounds__(256) void k3b(
    const float* __restrict__ attn, const void* __restrict__ in2dv,
    const bfu* __restrict__ vsT, const bfu* __restrict__ vgT,
    const bfu* __restrict__ rot, const bfu* __restrict__ trans,
    bfu* __restrict__ finalb, const u32* __restrict__ flags) {
    int q = blockIdx.x, t = threadIdx.x;
    bool f32m = flags[0] != 0u;
    __shared__ __align__(16) float lgs[12 * 776];  // attn f32, 37.2 KB
    __shared__ float rpg[288];
    __shared__ float rots[9], trs[3];

    for (int h = 0; h < 12; ++h)
        for (int k = t; k < 768; k += 256)
            lgs[h * 776 + k] = attn[(size_t)q * 9216 + h * 768 + k];
    if (t < 9)  rots[t] = bf2f(rot[q * 9 + t]);
    if (t >= 16 && t < 19) trs[t - 16] = bf2f(trans[q * 3 + t - 16]);
    __syncthreads();

    // res_2d: thread owns c-pair cp and head-trio {h0, h0+4, h0+8}
    int cp = t & 63, h0 = t >> 6;
    float p00 = 0, p01 = 0, p10 = 0, p11 = 0, p20 = 0, p21 = 0;
    if (f32m) {
        const float2* p2 = (const float2*)((const float*)in2dv + (size_t)q * 98304) + cp;
#pragma unroll 4
        for (int k = 0; k < 768; ++k) {
            float2 v = p2[(size_t)k * 64];
            float a0 = lgs[(h0 + 0) * 776 + k];
            float a1 = lgs[(h0 + 4) * 776 + k];
            float a2 = lgs[(h0 + 8) * 776 + k];
            p00 += a0 * v.x; p01 += a0 * v.y;
            p10 += a1 * v.x; p11 += a1 * v.y;
            p20 += a2 * v.x; p21 += a2 * v.y;
        }
    } else {
        const u32* pu = (const u32*)in2dv + (size_t)q * 49152 + cp;
#pragma unroll 4
        for (int k = 0; k < 768; ++k) {
            u32 u = pu[(size_t)k * 64];
            float vx = bflo(u), vy = bfhi(u);
            float a0 = lgs[(h0 + 0) * 776 + k];
            float a1 = lgs[(h0 + 4) * 776 + k];
            float a2 = lgs[(h0 + 8) * 776 + k];
            p00 += a0 * vx; p01 += a0 * vy;
            p10 += a1 * vx; p11 += a1 * vy;
            p20 += a2 * vx; p21 += a2 * vy;
        }
    }
    {
        bfu* fb = finalb + (size_t)q * 2112 + 576;
        *(u32*)&fb[(h0 + 0) * 128 + 2 * cp] = (u32)f2bf(p00) | ((u32)f2bf(p01) << 16);
        *(u32*)&fb[(h0 + 4) * 128 + 2 * cp] = (u32)f2bf(p10) | ((u32)f2bf(p11) << 16);
        *(u32*)&fb[(h0 + 8) * 128 + 2 * cp] = (u32)f2bf(p20) | ((u32)f2bf(p21) << 16);
    }

    // res_scalar (16/h) + rp_g (24/h): 240 threads x 2 outputs (same h)
    if (t < 240) {
        int o0 = 2 * t;
        int h = o0 / 40, r0 = o0 - h * 40, r1 = r0 + 1;
        const bfu* rowA = (r0 < 16) ? (vsT + (size_t)(h * 16 + r0) * 768)
                                    : (vgT + (size_t)(h * 24 + r0 - 16) * 768);
        const bfu* rowB = (r1 < 16) ? (vsT + (size_t)(h * 16 + r1) * 768)
                                    : (vgT + (size_t)(h * 24 + r1 - 16) * 768);
        float aA = 0.f, aB = 0.f;
        for (int kb = 0; kb < 96; ++kb) {
            int k8 = kb * 8;
            float4 aL = *(const float4*)&lgs[h * 776 + k8];
            float4 aH = *(const float4*)&lgs[h * 776 + k8 + 4];
            uint4 uA = *(const uint4*)(rowA + k8);
            uint4 uB = *(const uint4*)(rowB + k8);
            aA += aL.x * bflo(uA.x) + aL.y * bfhi(uA.x)
                + aL.z * bflo(uA.y) + aL.w * bfhi(uA.y)
                + aH.x * bflo(uA.z) + aH.y * bfhi(uA.z)
                + aH.z * bflo(uA.w) + aH.w * bfhi(uA.w);
            aB += aL.x * bflo(uB.x) + aL.y * bfhi(uB.x)
                + aL.z * bflo(uB.y) + aL.w * bfhi(uB.y)
                + aH.x * bflo(uB.z) + aH.y * bfhi(uB.z)
                + aH.z * bflo(uB.w) + aH.w * bfhi(uB.w);
        }
        if (r0 < 16) finalb[(size_t)q * 2112 + h * 16 + r0] = f2bf(aA);
        else rpg[h * 24 + r0 - 16] = aA;
        if (r1 < 16) finalb[(size_t)q * 2112 + h * 16 + r1] = f2bf(aB);
        else rpg[h * 24 + r1 - 16] = aB;
    }
    __syncthreads();

    if (t < 96) {
        int h = t >> 3, p = t & 7;
        float v0 = rpg[h * 24 + p * 3 + 0] - trs[0];
        float v1 = rpg[h * 24 + p * 3 + 1] - trs[1];
        float v2 = rpg[h * 24 + p * 3 + 2] - trs[2];
        float r0 = rots[0] * v0 + rots[3] * v1 + rots[6] * v2;
        float r1 = rots[1] * v0 + rots[4] * v1 + rots[7] * v2;
        float r2 = rots[2] * v0 + rots[5] * v1 + rots[8] * v2;
        float nn = sqrtf(fmaxf(r0 * r0 + r1 * r1 + r2 * r2, 1e-16f));
        size_t fb = (size_t)q * 2112;
        finalb[fb + 192 + h * 8 + p] = f2bf(r0);
        finalb[fb + 288 + h * 8 + p] = f2bf(r1);
        finalb[fb + 384 + h * 8 + p] = f2bf(r2);
        finalb[fb + 480 + h * 8 + p] = f2bf(nn);
    }
}

// ---------------------------------------------------------------------------
__global__ __launch_bounds__(128) void k_ln(
    const bfu* __restrict__ a, const bfu* __restrict__ b,
    const bfu* __restrict__ sc, const bfu* __restrict__ bi,
    bfu* __restrict__ outb, void* __restrict__ outf, const u32* __restrict__ flags) {
    int r = blockIdx.x, t = threadIdx.x;
    __shared__ float red[2][2];
    float x[3];
    float s = 0.f, ss = 0.f;
#pragma unroll
    for (int i = 0; i < 3; ++i) {
        int c = t + i * 128;
        float v = bf2f(a[(size_t)r * 384 + c]) + bf2f(b[(size_t)r * 384 + c]);
        x[i] = v; s += v; ss += v * v;
    }
#pragma unroll
    for (int off = 1; off < 64; off <<= 1) { s += __shfl_xor(s, off); ss += __shfl_xor(ss, off); }
    int w = t >> 6;
    if ((t & 63) == 0) { red[w][0] = s; red[w][1] = ss; }
    __syncthreads();
    s = red[0][0] + red[1][0];
    ss = red[0][1] + red[1][1];
    float mu = s * (1.0f / 384.0f);
    float var = ss * (1.0f / 384.0f) - mu * mu;
    float rstd = rsqrtf(var + 1e-5f);
    bool f32o = flags[1] != 0u;
#pragma unroll
    for (int i = 0; i < 3; ++i) {
        int c = t + i * 128;
        float v = (x[i] - mu) * rstd * bf2f(sc[c]) + bf2f(bi[c]);
        outb[(size_t)r * 384 + c] = f2bf(v);
        if (outf) {
            if (f32o) ((float*)outf)[(size_t)r * 396 + c] = v;
            else      ((bfu*)outf)[(size_t)r * 396 + c] = f2bf(v);
        }
    }
}

// ---------------------------------------------------------------------------
__global__ __launch_bounds__(64) void k_quat(
    const bfu* __restrict__ act2,
    const bfu* __restrict__ rot, const bfu* __restrict__ trans,
    const bfu* __restrict__ wq, const bfu* __restrict__ bq,
    void* __restrict__ doutv, const u32* __restrict__ flags) {
    int r = blockIdx.x, t = threadIdx.x;
    float acc[6] = {};
    for (int i = 0; i < 6; ++i) {
        int k = t + i * 64;
        float xv = bf2f(act2[(size_t)r * 384 + k]);
#pragma unroll
        for (int o = 0; o < 6; ++o) acc[o] += xv * bf2f(wq[k * 6 + o]);
    }
#pragma unroll
    for (int o = 0; o < 6; ++o) {
#pragma unroll
        for (int off = 1; off < 64; off <<= 1) acc[o] += __shfl_xor(acc[o], off);
    }
    if (t == 0) {
        bool f32o = flags[1] != 0u;
        float v[6];
        for (int o = 0; o < 6; ++o) v[o] = acc[o] + bf2f(bq[o]);
        float w_ = 1.0f, x_ = v[0], y_ = v[1], z_ = v[2];
        float inv = rsqrtf(w_ * w_ + x_ * x_ + y_ * y_ + z_ * z_);
        w_ *= inv; x_ *= inv; y_ *= inv; z_ *= inv;
        float U[9];
        U[0] = 1 - 2 * (y_ * y_ + z_ * z_); U[1] = 2 * (x_ * y_ - w_ * z_); U[2] = 2 * (x_ * z_ + w_ * y_);
        U[3] = 2 * (x_ * y_ + w_ * z_); U[4] = 1 - 2 * (x_ * x_ + z_ * z_); U[5] = 2 * (y_ * z_ - w_ * x_);
        U[6] = 2 * (x_ * z_ - w_ * y_); U[7] = 2 * (y_ * z_ + w_ * x_); U[8] = 1 - 2 * (x_ * x_ + y_ * y_);
        float R[9];
        for (int i = 0; i < 9; ++i) R[i] = bf2f(rot[r * 9 + i]);
        for (int i = 0; i < 3; ++i)
            for (int j = 0; j < 3; ++j) {
                float sum = R[i * 3] * U[j] + R[i * 3 + 1] * U[3 + j] + R[i * 3 + 2] * U[6 + j];
                if (f32o) ((float*)doutv)[(size_t)r * 396 + 384 + i * 3 + j] = sum;
                else      ((bfu*)doutv)[(size_t)r * 396 + 384 + i * 3 + j] = f2bf(sum);
            }
        for (int i = 0; i < 3; ++i) {
            float sum = R[i * 3] * v[3] + R[i * 3 + 1] * v[4] + R[i * 3 + 2] * v[5] + bf2f(trans[r * 3 + i]);
            if (f32o) ((float*)doutv)[(size_t)r * 396 + 393 + i] = sum;
            else      ((bfu*)doutv)[(size_t)r * 396 + 393 + i] = f2bf(sum);
        }
    }
}

// ---------------------------------------------------------------------------
extern "C" void kernel_launch(void* const* d_in, const int* in_sizes, int n_in,
                              void* d_out, int out_size, void* d_ws, size_t ws_size,
                              hipStream_t stream) {
    (void)in_sizes; (void)n_in; (void)out_size; (void)ws_size;

    char* ws = (char*)d_ws;
    bfu* pl      = (bfu*)(ws + OFF_PL);
    float* fq    = (float*)(ws + OFF_FQ);
    float* gkT   = (float*)(ws + OFF_GKT);
    bfu* vsT     = (bfu*)(ws + OFF_VST);
    bfu* vgT     = (bfu*)(ws + OFF_VGT);
    float* attn  = (float*)(ws + OFF_ATTN);
    bfu* finalb  = (bfu*)(ws + OFF_FINAL);
    bfu* attnout = (bfu*)(ws + OFF_ATTNOUT);
    bfu* act     = (bfu*)(ws + OFF_ACT);
    bfu* x1      = (bfu*)(ws + OFF_X1);
    bfu* x2      = (bfu*)(ws + OFF_X2);
    bfu* act2    = x2;
    bfu* wcat    = (bfu*)(ws + OFF_WCAT);
    bfu* bcat    = (bfu*)(ws + OFF_BCAT);
    bfu* conv    = (bfu*)(ws + OFF_CONV);
    u32* flags   = (u32*)(ws + OFF_FLAG);

    static const int offs[30] = {
        0, 294912, 295680, 302592, 304896, 360192, 360336, 415632, 415776,
        526368, 526656, 600384, 674112, 747840, 747852, 749388, 749400,
        1560408, 1560792, 1561176, 1561560, 1709016, 1709400, 1856856, 1857240,
        2004696, 2005080, 2005464, 2005848, 2008152
    };
    const bfu* c_in1d = conv + offs[0];
    const bfu* c_mask = conv + offs[1];
    const bfu* c_rot  = conv + offs[2];
    const bfu* c_trns = conv + offs[3];
    const bfu* c_wqp  = conv + offs[4];
    const bfu* c_bqp  = conv + offs[5];
    const bfu* c_wkp  = conv + offs[6];
    const bfu* c_bkp  = conv + offs[7];
    const bfu* c_wvp  = conv + offs[8];
    const bfu* c_bvp  = conv + offs[9];
    const bfu* c_wqs  = conv + offs[10];
    const bfu* c_wks  = conv + offs[11];
    const bfu* c_wvs  = conv + offs[12];
    const bfu* c_tpw  = conv + offs[13];
    const bfu* c_w2d  = conv + offs[14];
    const bfu* c_b2d  = conv + offs[15];
    const bfu* c_wout = conv + offs[16];
    const bfu* c_bout = conv + offs[17];
    const bfu* c_ln1s = conv + offs[18];
    const bfu* c_ln1b = conv + offs[19];
    const bfu* c_wt1  = conv + offs[20];
    const bfu* c_bt1  = conv + offs[21];
    const bfu* c_wt2  = conv + offs[22];
    const bfu* c_bt2  = conv + offs[23];
    const bfu* c_wt3  = conv + offs[24];
    const bfu* c_bt3  = conv + offs[25];
    const bfu* c_ln2s = conv + offs[26];
    const bfu* c_ln2b = conv + offs[27];
    const bfu* c_wqt  = conv + offs[28];
    const bfu* c_bqt  = conv + offs[29];

    P30 ps;
    ps.p[0] = d_in[0];
    for (int i = 1; i < 30; ++i) ps.p[i] = d_in[i + 1];
    const void* in2d = d_in[1];

    k_convert<<<(CONV_TOTAL + 255) / 256, 256, 0, stream>>>(ps, conv, flags);
    k_concat<<<1733, 256, 0, stream>>>(c_wqs, c_wks, c_wvs, c_wqp, c_bqp, c_wkp, c_bkp,
                                       c_wvp, c_bvp, wcat, bcat);
    k_gemm64<0><<<dim3(18, 12), 256, 0, stream>>>(c_in1d, wcat, bcat, pl, 384, 1152);
    k_rigid<<<768, 64, 0, stream>>>(pl, c_rot, c_trns, c_tpw, c_b2d, fq, gkT, vsT, vgT);
    k_fused<<<768, 256, 0, stream>>>(fq, gkT, in2d, c_w2d, c_mask, attn, flags);
    k3b<<<768, 256, 0, stream>>>(attn, in2d, vsT, vgT, c_rot, c_trns, finalb, flags);
    k_gemm64<0><<<dim3(6, 12), 256, 0, stream>>>(finalb, c_wout, c_bout, attnout, 2112, 384);
    k_ln<<<768, 128, 0, stream>>>(c_in1d, attnout, c_ln1s, c_ln1b, act, nullptr, flags);
    k_gemm64<1><<<dim3(6, 12), 256, 0, stream>>>(act, c_wt1, c_bt1, x1, 384, 384);
    k_gemm64<1><<<dim3(6, 12), 256, 0, stream>>>(x1, c_wt2, c_bt2, x2, 384, 384);
    k_gemm64<0><<<dim3(6, 12), 256, 0, stream>>>(x2, c_wt3, c_bt3, x1, 384, 384);
    k_ln<<<768, 128, 0, stream>>>(act, x1, c_ln2s, c_ln2b, act2, d_out, flags);
    k_quat<<<768, 64, 0, stream>>>(act2, c_rot, c_trns, c_wqt, c_bqt, d_out, flags);
}

// Round 4
// 925.977 us; speedup vs baseline: 1.0735x; 1.0735x over previous
//
#include <hip/hip_runtime.h>

// ---------------------------------------------------------------------------
// FoldIteration (AlphaFold IPA + transition + rigid update).
// N=768, C=384, C2=128, H=12, PQK=4, PV=8, CQK=16, CV=16. Out: [768, 396].
// Dtype-dual: probes input dtype (f32 vs bf16) on device.
// R4: k3b res_2d restructured for memory-level parallelism:
//     (k8,cq) thread mapping, float4 streams, shfl+LDS-atomic reduction.
// ---------------------------------------------------------------------------

typedef unsigned short bfu;
typedef unsigned int u32;

__device__ __forceinline__ float bf2f(bfu u) {
    return __uint_as_float(((u32)u) << 16);
}
__device__ __forceinline__ bfu f2bf(float f) {
    u32 x = __float_as_uint(f);
    u32 r = x + 0x7fffu + ((x >> 16) & 1u);
    return (bfu)(r >> 16);
}
__device__ __forceinline__ float bflo(u32 u) { return __uint_as_float(u << 16); }
__device__ __forceinline__ float bfhi(u32 u) { return __uint_as_float(u & 0xffff0000u); }

// ---- workspace layout (bytes) ----
#define OFF_PL      0u               // pl bf16 [768][1152]
#define OFF_FQ      1769472u         // fq f32 [768][384]
#define OFF_GKT     2949120u         // gkT f32 [384][768]   (transposed!)
#define OFF_VST     4128768u         // vsT bf16 [192][768]
#define OFF_VGT     4423680u         // vgT bf16 [288][768]
#define OFF_ATTN    4866048u         // attn f32 [768][12][768]
#define OFF_FINAL   33177600u        // final bf16 [768][2112]
#define OFF_ATTNOUT 36421632u        // bf16 [768][384]
#define OFF_ACT     37011456u        // bf16 [768][384]
#define OFF_X1      37601280u        // bf16 [768][384]
#define OFF_X2      38191104u        // bf16 [768][384] (act2 after gemm3)
#define OFF_WCAT    38780928u        // bf16 [384][1152]
#define OFF_BCAT    39665664u        // bf16 [1152]
#define OFF_CONV    39667968u        // bf16 canonical copies of 30 small inputs
#define OFF_FLAG    43684288u        // u32 flags[2]

#define CONV_TOTAL 2008158

struct P30 { const void* p[30]; };

static __device__ const int kEnd[30] = {
    294912, 295680, 302592, 304896, 360192, 360336, 415632, 415776,
    526368, 526656, 600384, 674112, 747840, 747852, 749388, 749400,
    1560408, 1560792, 1561176, 1561560, 1709016, 1709400, 1856856, 1857240,
    2004696, 2005080, 2005464, 2005848, 2008152, 2008158
};

// ---------------------------------------------------------------------------
__global__ __launch_bounds__(256) void k_convert(P30 ps, bfu* __restrict__ conv,
                                                 u32* __restrict__ flags) {
    u32 pm = *(const u32*)ps.p[1];    // mask[0]
    u32 pp = *(const u32*)ps.p[18];   // ln1_s[0]
    u32 fA = (pm == 0x3F800000u) ? 1u : 0u;
    u32 fB = (pp == 0x3F800000u) ? 1u : 0u;
    int idx = blockIdx.x * 256 + threadIdx.x;
    if (idx == 0) { flags[0] = fA; flags[1] = fA & fB; }
    if (idx >= CONV_TOTAL) return;
    int t = 0;
    while (idx >= kEnd[t]) ++t;
    int local = idx - (t ? kEnd[t - 1] : 0);
    u32 f = (t < 4) ? fA : fB;
    float v = f ? ((const float*)ps.p[t])[local]
                : bf2f(((const bfu*)ps.p[t])[local]);
    conv[idx] = f2bf(v);
}

// ---------------------------------------------------------------------------
__global__ __launch_bounds__(256) void k_concat(
    const bfu* __restrict__ wqs, const bfu* __restrict__ wks, const bfu* __restrict__ wvs,
    const bfu* __restrict__ wqp, const bfu* __restrict__ bqp,
    const bfu* __restrict__ wkp, const bfu* __restrict__ bkp,
    const bfu* __restrict__ wvp, const bfu* __restrict__ bvp,
    bfu* __restrict__ wcat, bfu* __restrict__ bcat) {
    int idx = blockIdx.x * 256 + threadIdx.x;
    if (idx < 384 * 1152) {
        int row = idx / 1152, col = idx - row * 1152;
        bfu v;
        if      (col < 192) v = wqs[row * 192 + col];
        else if (col < 384) v = wks[row * 192 + col - 192];
        else if (col < 576) v = wvs[row * 192 + col - 384];
        else if (col < 720) v = wqp[row * 144 + col - 576];
        else if (col < 864) v = wkp[row * 144 + col - 720];
        else                v = wvp[row * 288 + col - 864];
        wcat[idx] = v;
    } else if (idx < 384 * 1152 + 1152) {
        int col = idx - 384 * 1152;
        bfu v;
        if      (col < 576) v = 0;
        else if (col < 720) v = bqp[col - 576];
        else if (col < 864) v = bkp[col - 720];
        else                v = bvp[col - 864];
        bcat[col] = v;
    }
}

// ---------------------------------------------------------------------------
// 64x64 tiled GEMM, 256 threads, 4x4 micro, BK=32.
// ---------------------------------------------------------------------------
template <int RELU>
__global__ __launch_bounds__(256) void k_gemm64(
    const bfu* __restrict__ A, const bfu* __restrict__ W, const bfu* __restrict__ bias,
    bfu* __restrict__ out, int K, int M) {
    __shared__ float As[32][69];   // As[k][row]
    __shared__ float Ws[32][69];   // Ws[k][col]
    int t = threadIdx.x;
    int c0 = blockIdx.x * 64, r0 = blockIdx.y * 64;
    int tr = t >> 4, tc = t & 15;
    float acc[4][4] = {};
    for (int kc = 0; kc < K; kc += 32) {
#pragma unroll
        for (int i = 0; i < 4; ++i) {
            int idx = t + i * 256;
            int r = idx >> 4, c2 = idx & 15;
            u32 u = *(const u32*)&A[(size_t)(r0 + r) * K + kc + 2 * c2];
            As[2 * c2][r] = bflo(u); As[2 * c2 + 1][r] = bfhi(u);
        }
#pragma unroll
        for (int i = 0; i < 4; ++i) {
            int idx = t + i * 256;
            int r = idx >> 5, c2 = idx & 31;
            u32 u = *(const u32*)&W[(size_t)(kc + r) * M + c0 + 2 * c2];
            Ws[r][2 * c2] = bflo(u); Ws[r][2 * c2 + 1] = bfhi(u);
        }
        __syncthreads();
#pragma unroll
        for (int kk = 0; kk < 32; ++kk) {
            float x[4], w[4];
#pragma unroll
            for (int j = 0; j < 4; ++j) { x[j] = As[kk][4 * tr + j]; w[j] = Ws[kk][4 * tc + j]; }
#pragma unroll
            for (int a = 0; a < 4; ++a)
#pragma unroll
                for (int b = 0; b < 4; ++b) acc[a][b] += x[a] * w[b];
        }
        __syncthreads();
    }
    float bv[4];
#pragma unroll
    for (int b = 0; b < 4; ++b) bv[b] = bf2f(bias[c0 + 4 * tc + b]);
#pragma unroll
    for (int a = 0; a < 4; ++a) {
        float v[4];
#pragma unroll
        for (int b = 0; b < 4; ++b) {
            v[b] = acc[a][b] + bv[b];
            if (RELU) v[b] = fmaxf(v[b], 0.f);
        }
        uint2 pk;
        pk.x = (u32)f2bf(v[0]) | ((u32)f2bf(v[1]) << 16);
        pk.y = (u32)f2bf(v[2]) | ((u32)f2bf(v[3]) << 16);
        *(uint2*)&out[(size_t)(r0 + 4 * tr + a) * M + c0 + 4 * tc] = pk;
    }
}

// ---------------------------------------------------------------------------
// Per-residue rigid transforms + augmented QK features (gk stored TRANSPOSED).
// ---------------------------------------------------------------------------
__global__ __launch_bounds__(64) void k_rigid(
    const bfu* __restrict__ pl, const bfu* __restrict__ rot, const bfu* __restrict__ trans,
    const bfu* __restrict__ tpw, const bfu* __restrict__ b2d,
    float* __restrict__ fq, float* __restrict__ gkT,
    bfu* __restrict__ vsT, bfu* __restrict__ vgT) {
    int n = blockIdx.x, t = threadIdx.x;
    __shared__ float pls[1152];
    __shared__ float qgs[144], kgs[144];
    __shared__ float rs[9], ts3[3], pws[12], qns[12], kns[12];
    for (int i = t; i < 1152; i += 64) pls[i] = bf2f(pl[(size_t)n * 1152 + i]);
    if (t < 9)  rs[t] = bf2f(rot[n * 9 + t]);
    if (t < 3)  ts3[t] = bf2f(trans[n * 3 + t]);
    if (t < 12) pws[t] = 0.23570226039551584f * log1pf(expf(bf2f(tpw[t])));
    __syncthreads();
    for (int idx = t; idx < 144; idx += 64) {
        int h = idx / 12, r = idx - h * 12, p = r / 3, i = r - p * 3;
        float q0 = pls[576 + h * 12 + p], q1 = pls[576 + h * 12 + 4 + p], q2 = pls[576 + h * 12 + 8 + p];
        qgs[idx] = rs[i * 3 + 0] * q0 + rs[i * 3 + 1] * q1 + rs[i * 3 + 2] * q2 + ts3[i];
        float k0 = pls[720 + h * 12 + p], k1 = pls[720 + h * 12 + 4 + p], k2 = pls[720 + h * 12 + 8 + p];
        kgs[idx] = rs[i * 3 + 0] * k0 + rs[i * 3 + 1] * k1 + rs[i * 3 + 2] * k2 + ts3[i];
    }
    for (int idx = t; idx < 288; idx += 64) {
        int h = idx / 24, r = idx - h * 24, p = r / 3, i = r - p * 3;
        float v0 = pls[864 + h * 24 + p], v1 = pls[864 + h * 24 + 8 + p], v2 = pls[864 + h * 24 + 16 + p];
        float v = rs[i * 3 + 0] * v0 + rs[i * 3 + 1] * v1 + rs[i * 3 + 2] * v2 + ts3[i];
        vgT[(size_t)idx * 768 + n] = f2bf(v);
    }
    __syncthreads();
    if (t < 12) {
        float s = 0;
        for (int j = 0; j < 12; ++j) s += qgs[t * 12 + j] * qgs[t * 12 + j];
        qns[t] = s;
        s = 0;
        for (int j = 0; j < 12; ++j) s += kgs[t * 12 + j] * kgs[t * 12 + j];
        kns[t] = s;
    }
    __syncthreads();
    for (int idx = t; idx < 12 * 32; idx += 64) {
        int h = idx >> 5, j = idx & 31;
        float fv, gv;
        if (j < 16)      { fv = 0.25f * pls[h * 16 + j];      gv = pls[192 + h * 16 + j]; }
        else if (j < 28) { fv = qgs[h * 12 + j - 16];         gv = pws[h] * kgs[h * 12 + j - 16]; }
        else if (j == 28){ fv = -0.5f * pws[h] * qns[h];      gv = 1.0f; }
        else if (j == 29){ fv = 1.0f;                          gv = -0.5f * pws[h] * kns[h]; }
        else if (j == 30){ fv = bf2f(b2d[h]);                  gv = 1.0f; }
        else             { fv = 0.0f;                          gv = 0.0f; }
        fq[(size_t)n * 384 + idx] = fv;
        gkT[(size_t)idx * 768 + n] = gv;
    }
    for (int idx = t; idx < 192; idx += 64)
        vsT[(size_t)idx * 768 + n] = f2bf(pls[384 + idx]);
}

// ---------------------------------------------------------------------------
// k_fused: per-q block. logits + softmax, attn f32 out. No logits round-trip.
// ---------------------------------------------------------------------------
__global__ __launch_bounds__(256) void k_fused(
    const float* __restrict__ fq, const float* __restrict__ gkT,
    const void* __restrict__ in2dv, const bfu* __restrict__ w2d,
    const bfu* __restrict__ mask, float* __restrict__ attn,
    const u32* __restrict__ flags) {
    int q = blockIdx.x, t = threadIdx.x;
    bool f32m = flags[0] != 0u;
    __shared__ float lg[12 * 776];                 // 37.2 KB
    __shared__ __align__(16) float w2ds[12 * 128]; // [h][c] 6 KB
    __shared__ __align__(16) float fqs[384];       // 1.5 KB
    for (int i = t; i < 1536; i += 256) {
        int cc = i / 12, hh = i - cc * 12;
        w2ds[hh * 128 + cc] = bf2f(w2d[i]);
    }
    for (int i = t; i < 384; i += 256) fqs[i] = fq[(size_t)q * 384 + i];
    float mq = bf2f(mask[q]);
    __syncthreads();

    for (int ch = 0; ch < 3; ++ch) {
        int k = ch * 256 + t;
        float acc[12] = {};
        size_t base = ((size_t)q * 768 + k) * 128;
        if (f32m) {
            const float4* p = (const float4*)((const float*)in2dv + base);
#pragma unroll 16
            for (int cb = 0; cb < 32; ++cb) {
                float4 u = p[cb];
#pragma unroll
                for (int h = 0; h < 12; ++h) {
                    float4 w = *(const float4*)&w2ds[h * 128 + cb * 4];
                    acc[h] += u.x * w.x + u.y * w.y + u.z * w.z + u.w * w.w;
                }
            }
        } else {
            const uint2* p = (const uint2*)((const bfu*)in2dv + base);
#pragma unroll 16
            for (int cb = 0; cb < 32; ++cb) {
                uint2 u = p[cb];
                float f0 = bflo(u.x), f1 = bfhi(u.x), f2 = bflo(u.y), f3 = bfhi(u.y);
#pragma unroll
                for (int h = 0; h < 12; ++h) {
                    float4 w = *(const float4*)&w2ds[h * 128 + cb * 4];
                    acc[h] += f0 * w.x + f1 * w.y + f2 * w.z + f3 * w.w;
                }
            }
        }
        float mk = bf2f(mask[k]);
        float mterm = 100000.0f * (1.0f - mq * mk);
#pragma unroll 1
        for (int h = 0; h < 12; ++h) {
            float s = 0.f;
            const float* g = gkT + (size_t)(h * 32) * 768 + k;
            const float* f = fqs + h * 32;
#pragma unroll
            for (int c = 0; c < 32; ++c) s += g[(size_t)c * 768] * f[c];
            lg[h * 776 + k] = (s + acc[h] - mterm) * 0.5773502691896258f;
        }
    }
    __syncthreads();

    if (t < 192) {
        int h = t >> 4, g = t & 15;
        float m = -1e30f;
        for (int i = 0; i < 48; ++i) m = fmaxf(m, lg[h * 776 + g + i * 16]);
#pragma unroll
        for (int off = 1; off < 16; off <<= 1) m = fmaxf(m, __shfl_xor(m, off));
        float s = 0.f;
        for (int i = 0; i < 48; ++i) {
            float v = __expf(lg[h * 776 + g + i * 16] - m);
            lg[h * 776 + g + i * 16] = v;
            s += v;
        }
#pragma unroll
        for (int off = 1; off < 16; off <<= 1) s += __shfl_xor(s, off);
        float rinv = 1.0f / s;
        for (int i = 0; i < 48; ++i) lg[h * 776 + g + i * 16] *= rinv;
    }
    __syncthreads();
    for (int h = 0; h < 12; ++h)
        for (int k = t; k < 768; k += 256)
            attn[(size_t)q * 9216 + h * 768 + k] = lg[h * 776 + k];
}

// ---------------------------------------------------------------------------
// k3b (R4): per-q block. res_2d via (k8,cq) mapping: thread owns c-quad,
// strides k by 8 -> 96 iters of float4 loads, 12-head register accumulate,
// shfl_xor(32) pair-reduce + 4-way LDS atomicAdd. Then res_scalar/rp_g,
// rigid-inverse + norms, assemble final[q][2112] bf16.
// ---------------------------------------------------------------------------
__global__ __launch_bounds__(256) void k3b(
    const float* __restrict__ attn, const void* __restrict__ in2dv,
    const bfu* __restrict__ vsT, const bfu* __restrict__ vgT,
    const bfu* __restrict__ rot, const bfu* __restrict__ trans,
    bfu* __restrict__ finalb, const u32* __restrict__ flags) {
    int q = blockIdx.x, t = threadIdx.x;
    bool f32m = flags[0] != 0u;
    __shared__ __align__(16) float lgs[12 * 776];  // attn f32, 37.2 KB
    __shared__ float res2[12 * 128];               // 6 KB
    __shared__ float rpg[288];
    __shared__ float rots[9], trs[3];

    for (int h = 0; h < 12; ++h)
        for (int k = t; k < 768; k += 256)
            lgs[h * 776 + k] = attn[(size_t)q * 9216 + h * 768 + k];
    for (int i = t; i < 1536; i += 256) res2[i] = 0.f;
    if (t < 9)  rots[t] = bf2f(rot[q * 9 + t]);
    if (t >= 16 && t < 19) trs[t - 16] = bf2f(trans[q * 3 + t - 16]);
    __syncthreads();

    // ---- res_2d ----
    {
        int k8 = t >> 5, cq = t & 31;
        float4 acc[12];
#pragma unroll
        for (int h = 0; h < 12; ++h) acc[h] = make_float4(0.f, 0.f, 0.f, 0.f);
        if (f32m) {
            const float4* p = (const float4*)((const float*)in2dv + (size_t)q * 98304) + cq;
#pragma unroll 4
            for (int i = 0; i < 96; ++i) {
                int k = i * 8 + k8;
                float4 v = p[(size_t)k * 32];
#pragma unroll
                for (int h = 0; h < 12; ++h) {
                    float a = lgs[h * 776 + k];
                    acc[h].x += a * v.x; acc[h].y += a * v.y;
                    acc[h].z += a * v.z; acc[h].w += a * v.w;
                }
            }
        } else {
            const uint2* p = (const uint2*)((const bfu*)in2dv + (size_t)q * 98304) + cq;
#pragma unroll 4
            for (int i = 0; i < 96; ++i) {
                int k = i * 8 + k8;
                uint2 u = p[(size_t)k * 32];
                float v0 = bflo(u.x), v1 = bfhi(u.x), v2 = bflo(u.y), v3 = bfhi(u.y);
#pragma unroll
                for (int h = 0; h < 12; ++h) {
                    float a = lgs[h * 776 + k];
                    acc[h].x += a * v0; acc[h].y += a * v1;
                    acc[h].z += a * v2; acc[h].w += a * v3;
                }
            }
        }
        // combine k8 pairs within wave (lane ^ 32), then 4-way atomics
#pragma unroll
        for (int h = 0; h < 12; ++h) {
            acc[h].x += __shfl_xor(acc[h].x, 32);
            acc[h].y += __shfl_xor(acc[h].y, 32);
            acc[h].z += __shfl_xor(acc[h].z, 32);
            acc[h].w += __shfl_xor(acc[h].w, 32);
        }
        if ((t & 63) < 32) {
#pragma unroll
            for (int h = 0; h < 12; ++h) {
                atomicAdd(&res2[h * 128 + 4 * cq + 0], acc[h].x);
                atomicAdd(&res2[h * 128 + 4 * cq + 1], acc[h].y);
                atomicAdd(&res2[h * 128 + 4 * cq + 2], acc[h].z);
                atomicAdd(&res2[h * 128 + 4 * cq + 3], acc[h].w);
            }
        }
    }
    __syncthreads();
    // write res_2d block of final
    for (int i = t; i < 768; i += 256) {
        int h = i >> 6, c2 = i & 63;
        u32 pk = (u32)f2bf(res2[h * 128 + 2 * c2]) | ((u32)f2bf(res2[h * 128 + 2 * c2 + 1]) << 16);
        *(u32*)&finalb[(size_t)q * 2112 + 576 + h * 128 + 2 * c2] = pk;
    }

    // ---- res_scalar (16/h) + rp_g (24/h): 240 threads x 2 outputs ----
    if (t < 240) {
        int o0 = 2 * t;
        int h = o0 / 40, r0 = o0 - h * 40, r1 = r0 + 1;
        const bfu* rowA = (r0 < 16) ? (vsT + (size_t)(h * 16 + r0) * 768)
                                    : (vgT + (size_t)(h * 24 + r0 - 16) * 768);
        const bfu* rowB = (r1 < 16) ? (vsT + (size_t)(h * 16 + r1) * 768)
                                    : (vgT + (size_t)(h * 24 + r1 - 16) * 768);
        float aA = 0.f, aB = 0.f;
        for (int kb = 0; kb < 96; ++kb) {
            int k8 = kb * 8;
            float4 aL = *(const float4*)&lgs[h * 776 + k8];
            float4 aH = *(const float4*)&lgs[h * 776 + k8 + 4];
            uint4 uA = *(const uint4*)(rowA + k8);
            uint4 uB = *(const uint4*)(rowB + k8);
            aA += aL.x * bflo(uA.x) + aL.y * bfhi(uA.x)
                + aL.z * bflo(uA.y) + aL.w * bfhi(uA.y)
                + aH.x * bflo(uA.z) + aH.y * bfhi(uA.z)
                + aH.z * bflo(uA.w) + aH.w * bfhi(uA.w);
            aB += aL.x * bflo(uB.x) + aL.y * bfhi(uB.x)
                + aL.z * bflo(uB.y) + aL.w * bfhi(uB.y)
                + aH.x * bflo(uB.z) + aH.y * bfhi(uB.z)
                + aH.z * bflo(uB.w) + aH.w * bfhi(uB.w);
        }
        if (r0 < 16) finalb[(size_t)q * 2112 + h * 16 + r0] = f2bf(aA);
        else rpg[h * 24 + r0 - 16] = aA;
        if (r1 < 16) finalb[(size_t)q * 2112 + h * 16 + r1] = f2bf(aB);
        else rpg[h * 24 + r1 - 16] = aB;
    }
    __syncthreads();

    if (t < 96) {
        int h = t >> 3, p = t & 7;
        float v0 = rpg[h * 24 + p * 3 + 0] - trs[0];
        float v1 = rpg[h * 24 + p * 3 + 1] - trs[1];
        float v2 = rpg[h * 24 + p * 3 + 2] - trs[2];
        float r0 = rots[0] * v0 + rots[3] * v1 + rots[6] * v2;
        float r1 = rots[1] * v0 + rots[4] * v1 + rots[7] * v2;
        float r2 = rots[2] * v0 + rots[5] * v1 + rots[8] * v2;
        float nn = sqrtf(fmaxf(r0 * r0 + r1 * r1 + r2 * r2, 1e-16f));
        size_t fb = (size_t)q * 2112;
        finalb[fb + 192 + h * 8 + p] = f2bf(r0);
        finalb[fb + 288 + h * 8 + p] = f2bf(r1);
        finalb[fb + 384 + h * 8 + p] = f2bf(r2);
        finalb[fb + 480 + h * 8 + p] = f2bf(nn);
    }
}

// ---------------------------------------------------------------------------
__global__ __launch_bounds__(128) void k_ln(
    const bfu* __restrict__ a, const bfu* __restrict__ b,
    const bfu* __restrict__ sc, const bfu* __restrict__ bi,
    bfu* __restrict__ outb, void* __restrict__ outf, const u32* __restrict__ flags) {
    int r = blockIdx.x, t = threadIdx.x;
    __shared__ float red[2][2];
    float x[3];
    float s = 0.f, ss = 0.f;
#pragma unroll
    for (int i = 0; i < 3; ++i) {
        int c = t + i * 128;
        float v = bf2f(a[(size_t)r * 384 + c]) + bf2f(b[(size_t)r * 384 + c]);
        x[i] = v; s += v; ss += v * v;
    }
#pragma unroll
    for (int off = 1; off < 64; off <<= 1) { s += __shfl_xor(s, off); ss += __shfl_xor(ss, off); }
    int w = t >> 6;
    if ((t & 63) == 0) { red[w][0] = s; red[w][1] = ss; }
    __syncthreads();
    s = red[0][0] + red[1][0];
    ss = red[0][1] + red[1][1];
    float mu = s * (1.0f / 384.0f);
    float var = ss * (1.0f / 384.0f) - mu * mu;
    float rstd = rsqrtf(var + 1e-5f);
    bool f32o = flags[1] != 0u;
#pragma unroll
    for (int i = 0; i < 3; ++i) {
        int c = t + i * 128;
        float v = (x[i] - mu) * rstd * bf2f(sc[c]) + bf2f(bi[c]);
        outb[(size_t)r * 384 + c] = f2bf(v);
        if (outf) {
            if (f32o) ((float*)outf)[(size_t)r * 396 + c] = v;
            else      ((bfu*)outf)[(size_t)r * 396 + c] = f2bf(v);
        }
    }
}

// ---------------------------------------------------------------------------
__global__ __launch_bounds__(64) void k_quat(
    const bfu* __restrict__ act2,
    const bfu* __restrict__ rot, const bfu* __restrict__ trans,
    const bfu* __restrict__ wq, const bfu* __restrict__ bq,
    void* __restrict__ doutv, const u32* __restrict__ flags) {
    int r = blockIdx.x, t = threadIdx.x;
    float acc[6] = {};
    for (int i = 0; i < 6; ++i) {
        int k = t + i * 64;
        float xv = bf2f(act2[(size_t)r * 384 + k]);
#pragma unroll
        for (int o = 0; o < 6; ++o) acc[o] += xv * bf2f(wq[k * 6 + o]);
    }
#pragma unroll
    for (int o = 0; o < 6; ++o) {
#pragma unroll
        for (int off = 1; off < 64; off <<= 1) acc[o] += __shfl_xor(acc[o], off);
    }
    if (t == 0) {
        bool f32o = flags[1] != 0u;
        float v[6];
        for (int o = 0; o < 6; ++o) v[o] = acc[o] + bf2f(bq[o]);
        float w_ = 1.0f, x_ = v[0], y_ = v[1], z_ = v[2];
        float inv = rsqrtf(w_ * w_ + x_ * x_ + y_ * y_ + z_ * z_);
        w_ *= inv; x_ *= inv; y_ *= inv; z_ *= inv;
        float U[9];
        U[0] = 1 - 2 * (y_ * y_ + z_ * z_); U[1] = 2 * (x_ * y_ - w_ * z_); U[2] = 2 * (x_ * z_ + w_ * y_);
        U[3] = 2 * (x_ * y_ + w_ * z_); U[4] = 1 - 2 * (x_ * x_ + z_ * z_); U[5] = 2 * (y_ * z_ - w_ * x_);
        U[6] = 2 * (x_ * z_ - w_ * y_); U[7] = 2 * (y_ * z_ + w_ * x_); U[8] = 1 - 2 * (x_ * x_ + y_ * y_);
        float R[9];
        for (int i = 0; i < 9; ++i) R[i] = bf2f(rot[r * 9 + i]);
        for (int i = 0; i < 3; ++i)
            for (int j = 0; j < 3; ++j) {
                float sum = R[i * 3] * U[j] + R[i * 3 + 1] * U[3 + j] + R[i * 3 + 2] * U[6 + j];
                if (f32o) ((float*)doutv)[(size_t)r * 396 + 384 + i * 3 + j] = sum;
                else      ((bfu*)doutv)[(size_t)r * 396 + 384 + i * 3 + j] = f2bf(sum);
            }
        for (int i = 0; i < 3; ++i) {
            float sum = R[i * 3] * v[3] + R[i * 3 + 1] * v[4] + R[i * 3 + 2] * v[5] + bf2f(trans[r * 3 + i]);
            if (f32o) ((float*)doutv)[(size_t)r * 396 + 393 + i] = sum;
            else      ((bfu*)doutv)[(size_t)r * 396 + 393 + i] = f2bf(sum);
        }
    }
}

// ---------------------------------------------------------------------------
extern "C" void kernel_launch(void* const* d_in, const int* in_sizes, int n_in,
                              void* d_out, int out_size, void* d_ws, size_t ws_size,
                              hipStream_t stream) {
    (void)in_sizes; (void)n_in; (void)out_size; (void)ws_size;

    char* ws = (char*)d_ws;
    bfu* pl      = (bfu*)(ws + OFF_PL);
    float* fq    = (float*)(ws + OFF_FQ);
    float* gkT   = (float*)(ws + OFF_GKT);
    bfu* vsT     = (bfu*)(ws + OFF_VST);
    bfu* vgT     = (bfu*)(ws + OFF_VGT);
    float* attn  = (float*)(ws + OFF_ATTN);
    bfu* finalb  = (bfu*)(ws + OFF_FINAL);
    bfu* attnout = (bfu*)(ws + OFF_ATTNOUT);
    bfu* act     = (bfu*)(ws + OFF_ACT);
    bfu* x1      = (bfu*)(ws + OFF_X1);
    bfu* x2      = (bfu*)(ws + OFF_X2);
    bfu* act2    = x2;
    bfu* wcat    = (bfu*)(ws + OFF_WCAT);
    bfu* bcat    = (bfu*)(ws + OFF_BCAT);
    bfu* conv    = (bfu*)(ws + OFF_CONV);
    u32* flags   = (u32*)(ws + OFF_FLAG);

    static const int offs[30] = {
        0, 294912, 295680, 302592, 304896, 360192, 360336, 415632, 415776,
        526368, 526656, 600384, 674112, 747840, 747852, 749388, 749400,
        1560408, 1560792, 1561176, 1561560, 1709016, 1709400, 1856856, 1857240,
        2004696, 2005080, 2005464, 2005848, 2008152
    };
    const bfu* c_in1d = conv + offs[0];
    const bfu* c_mask = conv + offs[1];
    const bfu* c_rot  = conv + offs[2];
    const bfu* c_trns = conv + offs[3];
    const bfu* c_wqp  = conv + offs[4];
    const bfu* c_bqp  = conv + offs[5];
    const bfu* c_wkp  = conv + offs[6];
    const bfu* c_bkp  = conv + offs[7];
    const bfu* c_wvp  = conv + offs[8];
    const bfu* c_bvp  = conv + offs[9];
    const bfu* c_wqs  = conv + offs[10];
    const bfu* c_wks  = conv + offs[11];
    const bfu* c_wvs  = conv + offs[12];
    const bfu* c_tpw  = conv + offs[13];
    const bfu* c_w2d  = conv + offs[14];
    const bfu* c_b2d  = conv + offs[15];
    const bfu* c_wout = conv + offs[16];
    const bfu* c_bout = conv + offs[17];
    const bfu* c_ln1s = conv + offs[18];
    const bfu* c_ln1b = conv + offs[19];
    const bfu* c_wt1  = conv + offs[20];
    const bfu* c_bt1  = conv + offs[21];
    const bfu* c_wt2  = conv + offs[22];
    const bfu* c_bt2  = conv + offs[23];
    const bfu* c_wt3  = conv + offs[24];
    const bfu* c_bt3  = conv + offs[25];
    const bfu* c_ln2s = conv + offs[26];
    const bfu* c_ln2b = conv + offs[27];
    const bfu* c_wqt  = conv + offs[28];
    const bfu* c_bqt  = conv + offs[29];

    P30 ps;
    ps.p[0] = d_in[0];
    for (int i = 1; i < 30; ++i) ps.p[i] = d_in[i + 1];
    const void* in2d = d_in[1];

    k_convert<<<(CONV_TOTAL + 255) / 256, 256, 0, stream>>>(ps, conv, flags);
    k_concat<<<1733, 256, 0, stream>>>(c_wqs, c_wks, c_wvs, c_wqp, c_bqp, c_wkp, c_bkp,
                                       c_wvp, c_bvp, wcat, bcat);
    k_gemm64<0><<<dim3(18, 12), 256, 0, stream>>>(c_in1d, wcat, bcat, pl, 384, 1152);
    k_rigid<<<768, 64, 0, stream>>>(pl, c_rot, c_trns, c_tpw, c_b2d, fq, gkT, vsT, vgT);
    k_fused<<<768, 256, 0, stream>>>(fq, gkT, in2d, c_w2d, c_mask, attn, flags);
    k3b<<<768, 256, 0, stream>>>(attn, in2d, vsT, vgT, c_rot, c_trns, finalb, flags);
    k_gemm64<0><<<dim3(6, 12), 256, 0, stream>>>(finalb, c_wout, c_bout, attnout, 2112, 384);
    k_ln<<<768, 128, 0, stream>>>(c_in1d, attnout, c_ln1s, c_ln1b, act, nullptr, flags);
    k_gemm64<1><<<dim3(6, 12), 256, 0, stream>>>(act, c_wt1, c_bt1, x1, 384, 384);
    k_gemm64<1><<<dim3(6, 12), 256, 0, stream>>>(x1, c_wt2, c_bt2, x2, 384, 384);
    k_gemm64<0><<<dim3(6, 12), 256, 0, stream>>>(x2, c_wt3, c_bt3, x1, 384, 384);
    k_ln<<<768, 128, 0, stream>>>(act, x1, c_ln2s, c_ln2b, act2, d_out, flags);
    k_quat<<<768, 64, 0, stream>>>(act2, c_rot, c_trns, c_wqt, c_bqt, d_out, flags);
}